// Round 10
// baseline (258.639 us; speedup 1.0000x reference)
//
#include <hip/hip_runtime.h>
#include <hip/hip_bf16.h>

// B=2, T=2048, E=1024, H=16, D=64. Inputs f32 (+ int32 mask), output f32.
// Internal bf16 MFMA pipeline.
// Flash: round-7 structure verbatim (best measured: 88 us @ 2 blocks/CU).
// GEMMs: register-staged DOUBLE-BUFFERED LDS, ONE barrier/iter (r5-proven
// structure), f32->bf16 convert fused into QKV A-staging (convert kernel
// deleted). 4 dispatches total.

typedef __bf16 bf8_t  __attribute__((ext_vector_type(8)));
typedef __bf16 bf4_t  __attribute__((ext_vector_type(4)));
typedef float  f4_t   __attribute__((ext_vector_type(4)));

constexpr int Bb = 2, Tt = 2048, Hh = 16, Dd = 64;

#if __has_builtin(__builtin_amdgcn_exp2f)
#define EXP2F(x) __builtin_amdgcn_exp2f(x)
#else
#define EXP2F(x) exp2f(x)
#endif

// ------------------------------------------------------------ transpose+cast
__global__ __launch_bounds__(256) void transpose_kernel(
    const float* __restrict__ w0, const float* __restrict__ w1,
    const float* __restrict__ w2, const float* __restrict__ w3,
    __bf16* __restrict__ o0, __bf16* __restrict__ o1,
    __bf16* __restrict__ o2, __bf16* __restrict__ o3)
{
    const float* in; __bf16* out;
    switch (blockIdx.z) {
        case 0: in = w0; out = o0; break;
        case 1: in = w1; out = o1; break;
        case 2: in = w2; out = o2; break;
        default: in = w3; out = o3; break;
    }
    __shared__ float t[32][33];
    int x  = threadIdx.x & 31;
    int y0 = threadIdx.x >> 5;
    int bx = blockIdx.x * 32;
    int by = blockIdx.y * 32;
    #pragma unroll
    for (int i = 0; i < 4; i++) {
        int y = y0 + i * 8;
        t[y][x] = in[(size_t)(by + y) * 1024 + bx + x];
    }
    __syncthreads();
    #pragma unroll
    for (int i = 0; i < 4; i++) {
        int y = y0 + i * 8;
        out[(size_t)(bx + y) * 1024 + by + x] = (__bf16)t[x][y];
    }
}

// ---------------------------------------------------------------- GEMM body
// C[M,1024] = A[M,1024] @ Bt^T + bias. Tile TM x 128, BK=64, 256 threads
// (4 waves as 2x2). Double-buffered LDS, register-staged, ONE barrier/iter:
//   top: ds_write prefetched regs -> buf[par]; barrier; issue next-tile
//   global loads; compute. (Race-free: barrier i+1 orders iter-i reads
//   against iter-i+2 writes of the same parity.)
// AF32: A is f32 in global, converted to bf16 during ds_write (fused cast).
// LDS swizzle: row of 64 elems, chunk slot j holds k-chunk j^(row&7).
// mode 0: out[gr*1024+gc] f32;  mode 1: [B,H,T,D] bf16;
// mode 2: [B,H,D,T] bf16 (vectorized bf16x4 store along t).
template <int TM, bool AF32, typename OutT>
__device__ __forceinline__ void gemm_dbuf(const void* __restrict__ Ap,
                                          const __bf16* __restrict__ Bt,
                                          const float* __restrict__ bias,
                                          OutT* __restrict__ out,
                                          int mode, float oscale, int bx, int by)
{
    constexpr int NA = TM / 32;           // A chunks per thread (4 or 2)
    constexpr int NI = TM / 32;           // im tiles per wave
    alignas(16) __shared__ __bf16 As[2][TM * 64];
    alignas(16) __shared__ __bf16 Bs[2][128 * 64];

    const float*  Af = (const float*)Ap;
    const __bf16* Ab = (const __bf16*)Ap;

    int tid  = threadIdx.x;
    int lane = tid & 63;
    int quad = lane >> 4;
    int l16  = lane & 15;
    int wave = tid >> 6;
    int wm   = wave >> 1, wn = wave & 1;

    // staging coords: thread covers rows (tid>>3)+32*i, fixed chunk slot
    const int srow = tid >> 3;                       // 0..31
    const int co   = (((tid & 7) ^ (srow & 7)) * 8); // swizzled k-offset
    const int sdst = tid * 8;                        // + 2048*i

    f4_t acc[NI][4];
    #pragma unroll
    for (int i = 0; i < NI; i++)
        #pragma unroll
        for (int j = 0; j < 4; j++)
            acc[i][j] = f4_t{0.f, 0.f, 0.f, 0.f};

    // prefetch registers
    float4 arf[NA][2];   // f32 path
    bf8_t  arb[NA];      // bf16 path
    bf8_t  brg[4];

    // prime tile 0
    #pragma unroll
    for (int i = 0; i < NA; i++) {
        size_t off = (size_t)(by * TM + srow + 32 * i) * 1024 + co;
        if constexpr (AF32) {
            arf[i][0] = *reinterpret_cast<const float4*>(Af + off);
            arf[i][1] = *reinterpret_cast<const float4*>(Af + off + 4);
        } else {
            arb[i] = *reinterpret_cast<const bf8_t*>(Ab + off);
        }
    }
    #pragma unroll
    for (int i = 0; i < 4; i++)
        brg[i] = *reinterpret_cast<const bf8_t*>(
            Bt + (size_t)(bx * 128 + srow + 32 * i) * 1024 + co);

    for (int kt = 0; kt < 1024; kt += 64) {
        int par = (kt >> 6) & 1;
        // stage current tile from regs (cast if f32)
        #pragma unroll
        for (int i = 0; i < NA; i++) {
            bf8_t w;
            if constexpr (AF32) {
                w[0] = (__bf16)arf[i][0].x; w[1] = (__bf16)arf[i][0].y;
                w[2] = (__bf16)arf[i][0].z; w[3] = (__bf16)arf[i][0].w;
                w[4] = (__bf16)arf[i][1].x; w[5] = (__bf16)arf[i][1].y;
                w[6] = (__bf16)arf[i][1].z; w[7] = (__bf16)arf[i][1].w;
            } else {
                w = arb[i];
            }
            *reinterpret_cast<bf8_t*>(&As[par][sdst + 2048 * i]) = w;
        }
        #pragma unroll
        for (int i = 0; i < 4; i++)
            *reinterpret_cast<bf8_t*>(&Bs[par][sdst + 2048 * i]) = brg[i];
        __syncthreads();

        // prefetch next tile (issued after barrier)
        int ktn = (kt + 64 < 1024) ? kt + 64 : 0;
        #pragma unroll
        for (int i = 0; i < NA; i++) {
            size_t off = (size_t)(by * TM + srow + 32 * i) * 1024 + ktn + co;
            if constexpr (AF32) {
                arf[i][0] = *reinterpret_cast<const float4*>(Af + off);
                arf[i][1] = *reinterpret_cast<const float4*>(Af + off + 4);
            } else {
                arb[i] = *reinterpret_cast<const bf8_t*>(Ab + off);
            }
        }
        #pragma unroll
        for (int i = 0; i < 4; i++)
            brg[i] = *reinterpret_cast<const bf8_t*>(
                Bt + (size_t)(bx * 128 + srow + 32 * i) * 1024 + ktn + co);

        // compute on buf[par]
        bf8_t af[2][NI], bfr[2][4];
        #pragma unroll
        for (int c = 0; c < 2; c++) {
            #pragma unroll
            for (int im = 0; im < NI; im++) {
                int row = wm * (TM / 2) + im * 16 + l16;
                af[c][im] = *reinterpret_cast<const bf8_t*>(
                    &As[par][row * 64 + (((c * 4 + quad) ^ (row & 7)) * 8)]);
            }
            #pragma unroll
            for (int in_ = 0; in_ < 4; in_++) {
                int row = wn * 64 + in_ * 16 + l16;
                bfr[c][in_] = *reinterpret_cast<const bf8_t*>(
                    &Bs[par][row * 64 + (((c * 4 + quad) ^ (row & 7)) * 8)]);
            }
        }
        #pragma unroll
        for (int c = 0; c < 2; c++)
            #pragma unroll
            for (int im = 0; im < NI; im++)
                #pragma unroll
                for (int in_ = 0; in_ < 4; in_++)
                    acc[im][in_] = __builtin_amdgcn_mfma_f32_16x16x32_bf16(
                        af[c][im], bfr[c][in_], acc[im][in_], 0, 0, 0);
        // no trailing barrier: next iter writes the other parity.
    }

    #pragma unroll
    for (int im = 0; im < NI; im++) {
        #pragma unroll
        for (int in_ = 0; in_ < 4; in_++) {
            int gc  = bx * 128 + wn * 64 + in_ * 16 + l16;
            float bb = bias[gc];
            int gr0 = by * TM + wm * (TM / 2) + im * 16 + quad * 4;
            if (mode == 2) {
                int b = gr0 >> 11, t0 = gr0 & 2047;
                int h = gc >> 6,  d = gc & 63;
                bf4_t ov;
                #pragma unroll
                for (int r = 0; r < 4; r++)
                    ov[r] = (__bf16)(acc[im][in_][r] + bb);
                *reinterpret_cast<bf4_t*>(
                    (__bf16*)out + ((size_t)(b * Hh + h) * Dd + d) * Tt + t0) = ov;
            } else {
                #pragma unroll
                for (int r = 0; r < 4; r++) {
                    int gr  = gr0 + r;
                    float v = (acc[im][in_][r] + bb) * oscale;
                    size_t idx;
                    if (mode == 0) {
                        idx = (size_t)gr * 1024 + gc;
                    } else {
                        int b = gr >> 11, t = gr & 2047;
                        int h = gc >> 6,  d = gc & 63;
                        idx = ((size_t)(b * Hh + h) * Tt + t) * Dd + d;
                    }
                    out[idx] = (OutT)v;
                }
            }
        }
    }
}

__global__ __launch_bounds__(256, 2) void gemm_qkv_kernel(
    const float* __restrict__ A,
    const __bf16* __restrict__ WqT, const __bf16* __restrict__ WkT, const __bf16* __restrict__ WvT,
    const float* __restrict__ bq,  const float* __restrict__ bk,  const float* __restrict__ bv,
    __bf16* __restrict__ Qo, __bf16* __restrict__ Ko, __bf16* __restrict__ Vo)
{
    const __bf16* Bt; const float* bias; __bf16* out; int mode; float sc;
    // Q carries 0.125 * log2(e) so flash softmax runs in exp2 domain.
    if      (blockIdx.z == 0) { Bt = WqT; bias = bq; out = Qo; mode = 1; sc = 0.18033688011112042f; }
    else if (blockIdx.z == 1) { Bt = WkT; bias = bk; out = Ko; mode = 1; sc = 1.f; }
    else                      { Bt = WvT; bias = bv; out = Vo; mode = 2; sc = 1.f; }
    gemm_dbuf<128, true, __bf16>(A, Bt, bias, out, mode, sc, blockIdx.x, blockIdx.y);
}

__global__ __launch_bounds__(256, 2) void gemm_out_kernel(
    const __bf16* __restrict__ A, const __bf16* __restrict__ Bt,
    const float* __restrict__ bias, float* __restrict__ out)
{
    gemm_dbuf<64, false, float>(A, Bt, bias, out, 0, 1.f, blockIdx.x, blockIdx.y);
}

// ---------------------------------------------------------------- flash attn
// Round-7 structure verbatim. grid (T/128, H, B), 512 threads = 8 waves;
// wave w owns 16 queries over all keys. Dbuf LDS, one barrier/iter,
// reg-staged K/V, prefetch after the barrier, int32 mask -> MFMA C-init.
__global__ __launch_bounds__(512, 4) void flash_kernel(
    const __bf16* __restrict__ Qb, const __bf16* __restrict__ Kb,
    const __bf16* __restrict__ Vb, const int* __restrict__ mask,
    __bf16* __restrict__ Zb)
{
    alignas(16) __shared__ __bf16 Ks[2][64 * 64];   // swizzled, 8KB each
    alignas(16) __shared__ __bf16 Vs[2][64 * 64];
    alignas(16) __shared__ __bf16 Ps[8 * 16 * 72];  // per-wave P^T, 18KB

    int tid  = threadIdx.x;
    int lane = tid & 63;
    int wave = tid >> 6;
    int quad = lane >> 4;
    int l16  = lane & 15;
    int b = blockIdx.z, h = blockIdx.y;
    int bh = b * Hh + h;
    int qrow = blockIdx.x * 128 + wave * 16;

    int srow = tid >> 3, sj = tid & 7;
    const __bf16* kgp = Kb + ((size_t)bh * Tt + srow) * Dd + ((sj ^ (srow & 7)) * 8);
    const __bf16* vgp = Vb + ((size_t)bh * Dd + srow) * Tt + ((sj ^ (srow & 7)) * 8);
    const int sdst = tid * 8;

    bf8_t qf[2];
    #pragma unroll
    for (int c = 0; c < 2; c++)
        qf[c] = *reinterpret_cast<const bf8_t*>(
            Qb + ((size_t)bh * Tt + qrow + l16) * Dd + c * 32 + quad * 8);

    const int* mp = mask + ((size_t)b * Tt + qrow + l16) * Tt + quad * 4;

    float l_i = 0.f;
    f4_t o[4];
    #pragma unroll
    for (int d = 0; d < 4; d++) o[d] = f4_t{0.f, 0.f, 0.f, 0.f};

    __bf16* pw = Ps + wave * 16 * 72;

    bf8_t kreg = *reinterpret_cast<const bf8_t*>(kgp);
    bf8_t vreg = *reinterpret_cast<const bf8_t*>(vgp);
    int4 ireg[4];
    #pragma unroll
    for (int n = 0; n < 4; n++)
        ireg[n] = *reinterpret_cast<const int4*>(mp + n * 16);

    for (int kt = 0; kt < Tt; kt += 64) {
        int par = (kt >> 6) & 1;
        *reinterpret_cast<bf8_t*>(&Ks[par][sdst]) = kreg;
        *reinterpret_cast<bf8_t*>(&Vs[par][sdst]) = vreg;
        f4_t s[4];
        #pragma unroll
        for (int n = 0; n < 4; n++)
            s[n] = f4_t{ireg[n].x ? 0.f : -1e30f, ireg[n].y ? 0.f : -1e30f,
                        ireg[n].z ? 0.f : -1e30f, ireg[n].w ? 0.f : -1e30f};
        __syncthreads();

        int ktn = (kt + 64 < Tt) ? kt + 64 : 0;
        kreg = *reinterpret_cast<const bf8_t*>(kgp + (size_t)ktn * Dd);
        vreg = *reinterpret_cast<const bf8_t*>(vgp + ktn);
        #pragma unroll
        for (int n = 0; n < 4; n++)
            ireg[n] = *reinterpret_cast<const int4*>(mp + ktn + n * 16);

        #pragma unroll
        for (int c = 0; c < 2; c++)
            #pragma unroll
            for (int n = 0; n < 4; n++) {
                int krow = n * 16 + l16;
                bf8_t kf = *reinterpret_cast<const bf8_t*>(
                    &Ks[par][krow * 64 + (((c * 4 + quad) ^ (krow & 7)) * 8)]);
                s[n] = __builtin_amdgcn_mfma_f32_16x16x32_bf16(kf, qf[c], s[n], 0, 0, 0);
            }

        float rs = 0.f;
        #pragma unroll
        for (int n = 0; n < 4; n++) {
            bf4_t pv4;
            #pragma unroll
            for (int r = 0; r < 4; r++) {
                float p = EXP2F(s[n][r]);
                rs += p;
                pv4[r] = (__bf16)p;
            }
            *reinterpret_cast<bf4_t*>(&pw[l16 * 72 + n * 16 + quad * 4]) = pv4;
        }
        rs += __shfl_xor(rs, 16);
        rs += __shfl_xor(rs, 32);
        l_i += rs;

        #pragma unroll
        for (int c = 0; c < 2; c++) {
            bf8_t pf = *reinterpret_cast<const bf8_t*>(
                &pw[l16 * 72 + c * 32 + quad * 8]);
            #pragma unroll
            for (int ds = 0; ds < 4; ds++) {
                int vrow = ds * 16 + l16;
                bf8_t vf = *reinterpret_cast<const bf8_t*>(
                    &Vs[par][vrow * 64 + (((c * 4 + quad) ^ (vrow & 7)) * 8)]);
                o[ds] = __builtin_amdgcn_mfma_f32_16x16x32_bf16(vf, pf, o[ds], 0, 0, 0);
            }
        }
    }

    float inv = 1.f / fmaxf(l_i, 1e-30f);
    size_t zrow = ((size_t)b * Tt + qrow + l16) * 1024 + h * 64;
    #pragma unroll
    for (int ds = 0; ds < 4; ds++) {
        bf4_t ov;
        #pragma unroll
        for (int r = 0; r < 4; r++) ov[r] = (__bf16)(o[ds][r] * inv);
        *reinterpret_cast<bf4_t*>(Zb + zrow + ds * 16 + quad * 4) = ov;
    }
}

// ---------------------------------------------------------------- launch
extern "C" void kernel_launch(void* const* d_in, const int* in_sizes, int n_in,
                              void* d_out, int out_size, void* d_ws, size_t ws_size,
                              hipStream_t stream)
{
    (void)in_sizes; (void)n_in; (void)out_size; (void)ws_size;

    const float* embed = (const float*)d_in[0];
    const int*   mask  = (const int*)d_in[1];
    const float* Wq = (const float*)d_in[2];
    const float* bq = (const float*)d_in[3];
    const float* Wk = (const float*)d_in[4];
    const float* bk = (const float*)d_in[5];
    const float* Wv = (const float*)d_in[6];
    const float* bv = (const float*)d_in[7];
    const float* Wz = (const float*)d_in[8];
    const float* bz = (const float*)d_in[9];
    float* out = (float*)d_out;

    char* ws = (char*)d_ws;
    const size_t MB = (size_t)1024 * 1024;
    __bf16* WqT = (__bf16*)(ws + 0 * MB);
    __bf16* WkT = (__bf16*)(ws + 2 * MB);
    __bf16* WvT = (__bf16*)(ws + 4 * MB);
    __bf16* WzT = (__bf16*)(ws + 6 * MB);
    __bf16* Qb  = (__bf16*)(ws + 16 * MB);
    __bf16* Kb  = (__bf16*)(ws + 24 * MB);
    __bf16* Vb  = (__bf16*)(ws + 32 * MB);
    __bf16* Zb  = (__bf16*)(ws + 40 * MB);   // total 48MB

    transpose_kernel<<<dim3(32, 32, 4), 256, 0, stream>>>(Wq, Wk, Wv, Wz,
                                                          WqT, WkT, WvT, WzT);
    gemm_qkv_kernel<<<dim3(8, 32, 3), 256, 0, stream>>>(embed, WqT, WkT, WvT,
                                                        bq, bk, bv, Qb, Kb, Vb);
    flash_kernel<<<dim3(16, Hh, Bb), 512, 0, stream>>>(Qb, Kb, Vb, mask, Zb);
    gemm_out_kernel<<<dim3(8, 64, 1), 256, 0, stream>>>(Zb, WzT, bz, out);
}

// Round 11
// 231.364 us; speedup vs baseline: 1.1179x; 1.1179x over previous
//
#include <hip/hip_runtime.h>
#include <hip/hip_bf16.h>

// B=2, T=2048, E=1024, H=16, D=64. Inputs f32 (+ int32 mask), output f32.
// Internal bf16 MFMA pipeline.
// prep: ONE dispatch = embed f32->bf16 convert + 4x weight transpose+cast
//       + mask int32 -> 1-bit bitmask (1MB, L2-resident).
// GEMMs: round-7 ASYNC16 2-barrier structure verbatim (known good).
// Flash: round-7 structure; mask path replaced by u64 bitmask loads
//        (8 B/lane/iter vs 64) applied at the p-select step.

typedef __bf16 bf8_t  __attribute__((ext_vector_type(8)));
typedef __bf16 bf4_t  __attribute__((ext_vector_type(4)));
typedef float  f4_t   __attribute__((ext_vector_type(4)));

constexpr int Bb = 2, Tt = 2048, Hh = 16, Dd = 64;

#define ASYNC16(g, l)                                                        \
    __builtin_amdgcn_global_load_lds(                                        \
        (const __attribute__((address_space(1))) void*)(g),                  \
        (__attribute__((address_space(3))) void*)(l), 16, 0, 0)

#if __has_builtin(__builtin_amdgcn_exp2f)
#define EXP2F(x) __builtin_amdgcn_exp2f(x)
#else
#define EXP2F(x) exp2f(x)
#endif

// ---------------------------------------------------------------- prep
// blockIdx.x decode: [0,4096) transpose W (z>>10 = which matrix),
// [4096,5120) convert embed, [5120,6144) build bitmask.
__global__ __launch_bounds__(256) void prep_kernel(
    const float* __restrict__ embed, const int* __restrict__ mask,
    const float* __restrict__ w0, const float* __restrict__ w1,
    const float* __restrict__ w2, const float* __restrict__ w3,
    __bf16* __restrict__ o0, __bf16* __restrict__ o1,
    __bf16* __restrict__ o2, __bf16* __restrict__ o3,
    __bf16* __restrict__ Eb, unsigned* __restrict__ Mbits)
{
    int z = blockIdx.x;
    if (z < 4096) {
        const float* in; __bf16* out;
        switch (z >> 10) {
            case 0: in = w0; out = o0; break;
            case 1: in = w1; out = o1; break;
            case 2: in = w2; out = o2; break;
            default: in = w3; out = o3; break;
        }
        int rem = z & 1023;
        int bx = (rem & 31) * 32;      // n offset
        int by = (rem >> 5) * 32;      // k offset
        __shared__ float t[32][33];
        int x  = threadIdx.x & 31;
        int y0 = threadIdx.x >> 5;
        #pragma unroll
        for (int i = 0; i < 4; i++) {
            int y = y0 + i * 8;
            t[y][x] = in[(size_t)(by + y) * 1024 + bx + x];
        }
        __syncthreads();
        #pragma unroll
        for (int i = 0; i < 4; i++) {
            int y = y0 + i * 8;
            out[(size_t)(bx + y) * 1024 + by + x] = (__bf16)t[x][y];
        }
    } else if (z < 5120) {
        size_t base = (size_t)(z - 4096) * 4096;
        #pragma unroll
        for (int j = 0; j < 4; j++) {
            size_t i = base + j * 1024 + threadIdx.x * 4;
            float4 v = *reinterpret_cast<const float4*>(embed + i);
            bf4_t o = {(__bf16)v.x, (__bf16)v.y, (__bf16)v.z, (__bf16)v.w};
            *reinterpret_cast<bf4_t*>(Eb + i) = o;
        }
    } else {
        // word g covers mask[g*32 .. g*32+32)
        size_t g = (size_t)(z - 5120) * 256 + threadIdx.x;
        const int* mp = mask + g * 32;
        unsigned v = 0;
        #pragma unroll
        for (int i = 0; i < 8; i++) {
            int4 m4 = *reinterpret_cast<const int4*>(mp + i * 4);
            if (m4.x) v |= 1u << (i * 4 + 0);
            if (m4.y) v |= 1u << (i * 4 + 1);
            if (m4.z) v |= 1u << (i * 4 + 2);
            if (m4.w) v |= 1u << (i * 4 + 3);
        }
        Mbits[g] = v;
    }
}

// ---------------------------------------------------------------- GEMM body
// round-7 structure verbatim: ASYNC16 staging, 2 barriers/iter, XOR swizzle.
template <int TM, typename OutT>
__device__ __forceinline__ void gemm_body(const __bf16* __restrict__ A,
                                          const __bf16* __restrict__ Bt,
                                          const float* __restrict__ bias,
                                          OutT* __restrict__ out,
                                          int mode, float oscale, int bx, int by)
{
    constexpr int NI = TM / 32;
    alignas(16) __shared__ __bf16 As[TM * 64];
    alignas(16) __shared__ __bf16 Bs[128 * 64];

    int tid  = threadIdx.x;
    int lane = tid & 63;
    int quad = lane >> 4;
    int l16  = lane & 15;
    int wave = tid >> 6;
    int wm   = wave >> 1, wn = wave & 1;

    f4_t acc[NI][4];
    #pragma unroll
    for (int i = 0; i < NI; i++)
        #pragma unroll
        for (int j = 0; j < 4; j++)
            acc[i][j] = f4_t{0.f, 0.f, 0.f, 0.f};

    for (int kt = 0; kt < 1024; kt += 64) {
        #pragma unroll
        for (int i = 0; i < TM / 32; i++) {
            int c   = tid + 256 * i;
            int row = c >> 3, j = c & 7;
            ASYNC16(A + (size_t)(by * TM + row) * 1024 + kt + ((j ^ (row & 7)) * 8),
                    &As[c * 8]);
        }
        #pragma unroll
        for (int i = 0; i < 4; i++) {
            int c   = tid + 256 * i;
            int row = c >> 3, j = c & 7;
            ASYNC16(Bt + (size_t)(bx * 128 + row) * 1024 + kt + ((j ^ (row & 7)) * 8),
                    &Bs[c * 8]);
        }
        __syncthreads();

        bf8_t af[2][NI], bfr[2][4];
        #pragma unroll
        for (int c = 0; c < 2; c++) {
            #pragma unroll
            for (int im = 0; im < NI; im++) {
                int row = wm * (TM / 2) + im * 16 + l16;
                af[c][im] = *reinterpret_cast<const bf8_t*>(
                    &As[row * 64 + (((c * 4 + quad) ^ (row & 7)) * 8)]);
            }
            #pragma unroll
            for (int in_ = 0; in_ < 4; in_++) {
                int row = wn * 64 + in_ * 16 + l16;
                bfr[c][in_] = *reinterpret_cast<const bf8_t*>(
                    &Bs[row * 64 + (((c * 4 + quad) ^ (row & 7)) * 8)]);
            }
        }
        #pragma unroll
        for (int c = 0; c < 2; c++)
            #pragma unroll
            for (int im = 0; im < NI; im++)
                #pragma unroll
                for (int in_ = 0; in_ < 4; in_++)
                    acc[im][in_] = __builtin_amdgcn_mfma_f32_16x16x32_bf16(
                        af[c][im], bfr[c][in_], acc[im][in_], 0, 0, 0);
        __syncthreads();
    }

    #pragma unroll
    for (int im = 0; im < NI; im++) {
        #pragma unroll
        for (int in_ = 0; in_ < 4; in_++) {
            int gc  = bx * 128 + wn * 64 + in_ * 16 + l16;
            float bb = bias[gc];
            int gr0 = by * TM + wm * (TM / 2) + im * 16 + quad * 4;
            if (mode == 2) {
                int b = gr0 >> 11, t0 = gr0 & 2047;
                int h = gc >> 6,  d = gc & 63;
                bf4_t ov;
                #pragma unroll
                for (int r = 0; r < 4; r++)
                    ov[r] = (__bf16)(acc[im][in_][r] + bb);
                *reinterpret_cast<bf4_t*>(
                    (__bf16*)out + ((size_t)(b * Hh + h) * Dd + d) * Tt + t0) = ov;
            } else {
                #pragma unroll
                for (int r = 0; r < 4; r++) {
                    int gr  = gr0 + r;
                    float v = (acc[im][in_][r] + bb) * oscale;
                    size_t idx;
                    if (mode == 0) {
                        idx = (size_t)gr * 1024 + gc;
                    } else {
                        int b = gr >> 11, t = gr & 2047;
                        int h = gc >> 6,  d = gc & 63;
                        idx = ((size_t)(b * Hh + h) * Tt + t) * Dd + d;
                    }
                    out[idx] = (OutT)v;
                }
            }
        }
    }
}

__global__ __launch_bounds__(256) void gemm_qkv_kernel(
    const __bf16* __restrict__ A,
    const __bf16* __restrict__ WqT, const __bf16* __restrict__ WkT, const __bf16* __restrict__ WvT,
    const float* __restrict__ bq,  const float* __restrict__ bk,  const float* __restrict__ bv,
    __bf16* __restrict__ Qo, __bf16* __restrict__ Ko, __bf16* __restrict__ Vo)
{
    const __bf16* Bt; const float* bias; __bf16* out; int mode; float sc;
    // Q carries 0.125 * log2(e) so flash softmax runs in exp2 domain.
    if      (blockIdx.z == 0) { Bt = WqT; bias = bq; out = Qo; mode = 1; sc = 0.18033688011112042f; }
    else if (blockIdx.z == 1) { Bt = WkT; bias = bk; out = Ko; mode = 1; sc = 1.f; }
    else                      { Bt = WvT; bias = bv; out = Vo; mode = 2; sc = 1.f; }
    gemm_body<128, __bf16>(A, Bt, bias, out, mode, sc, blockIdx.x, blockIdx.y);
}

__global__ __launch_bounds__(256) void gemm_out_kernel(
    const __bf16* __restrict__ A, const __bf16* __restrict__ Bt,
    const float* __restrict__ bias, float* __restrict__ out)
{
    gemm_body<64, float>(A, Bt, bias, out, 0, 1.f, blockIdx.x, blockIdx.y);
}

// ---------------------------------------------------------------- flash attn
// Round-7 structure; mask via bitmask u64 (bits [kt,kt+64) of query row).
// grid (T/128, H, B), 512 threads = 8 waves. Dbuf LDS, one barrier/iter,
// reg-staged K/V prefetch issued after the barrier.
__global__ __launch_bounds__(512, 4) void flash_kernel(
    const __bf16* __restrict__ Qb, const __bf16* __restrict__ Kb,
    const __bf16* __restrict__ Vb, const unsigned* __restrict__ Mbits,
    __bf16* __restrict__ Zb)
{
    alignas(16) __shared__ __bf16 Ks[2][64 * 64];   // swizzled, 8KB each
    alignas(16) __shared__ __bf16 Vs[2][64 * 64];
    alignas(16) __shared__ __bf16 Ps[8 * 16 * 72];  // per-wave P^T, 18KB

    int tid  = threadIdx.x;
    int lane = tid & 63;
    int wave = tid >> 6;
    int quad = lane >> 4;
    int l16  = lane & 15;
    int b = blockIdx.z, h = blockIdx.y;
    int bh = b * Hh + h;
    int qrow = blockIdx.x * 128 + wave * 16;

    int srow = tid >> 3, sj = tid & 7;
    const __bf16* kgp = Kb + ((size_t)bh * Tt + srow) * Dd + ((sj ^ (srow & 7)) * 8);
    const __bf16* vgp = Vb + ((size_t)bh * Dd + srow) * Tt + ((sj ^ (srow & 7)) * 8);
    const int sdst = tid * 8;

    bf8_t qf[2];
    #pragma unroll
    for (int c = 0; c < 2; c++)
        qf[c] = *reinterpret_cast<const bf8_t*>(
            Qb + ((size_t)bh * Tt + qrow + l16) * Dd + c * 32 + quad * 8);

    // bitmask row for this lane's query: 64 words/row, u64 per 64-key tile
    const unsigned* bmp = Mbits + ((size_t)b * Tt + qrow + l16) * 64;

    float l_i = 0.f;
    f4_t o[4];
    #pragma unroll
    for (int d = 0; d < 4; d++) o[d] = f4_t{0.f, 0.f, 0.f, 0.f};

    __bf16* pw = Ps + wave * 16 * 72;

    // prime: tile 0 into regs
    bf8_t kreg = *reinterpret_cast<const bf8_t*>(kgp);
    bf8_t vreg = *reinterpret_cast<const bf8_t*>(vgp);
    unsigned long long mreg = *reinterpret_cast<const unsigned long long*>(bmp);

    for (int kt = 0; kt < Tt; kt += 64) {
        int par = (kt >> 6) & 1;
        *reinterpret_cast<bf8_t*>(&Ks[par][sdst]) = kreg;
        *reinterpret_cast<bf8_t*>(&Vs[par][sdst]) = vreg;
        // per-n 4-bit nibbles for this lane's quad, captured before reload
        unsigned nib[4];
        #pragma unroll
        for (int n = 0; n < 4; n++)
            nib[n] = (unsigned)(mreg >> (n * 16 + quad * 4)) & 0xFu;
        __syncthreads();

        // prefetch next tile (issued after barrier -> not drained by it)
        int ktn = (kt + 64 < Tt) ? kt + 64 : 0;
        kreg = *reinterpret_cast<const bf8_t*>(kgp + (size_t)ktn * Dd);
        vreg = *reinterpret_cast<const bf8_t*>(vgp + ktn);
        mreg = *reinterpret_cast<const unsigned long long*>(bmp + (ktn >> 5));

        // S^T = K Q^T : 4 key-subtiles x 2 d-chunks
        f4_t s[4];
        #pragma unroll
        for (int n = 0; n < 4; n++) s[n] = f4_t{0.f, 0.f, 0.f, 0.f};
        #pragma unroll
        for (int c = 0; c < 2; c++)
            #pragma unroll
            for (int n = 0; n < 4; n++) {
                int krow = n * 16 + l16;
                bf8_t kf = *reinterpret_cast<const bf8_t*>(
                    &Ks[par][krow * 64 + (((c * 4 + quad) ^ (krow & 7)) * 8)]);
                s[n] = __builtin_amdgcn_mfma_f32_16x16x32_bf16(kf, qf[c], s[n], 0, 0, 0);
            }

        // p = mask-bit ? exp2(s) : 0; row-sum via 2 shuffles; P^T -> LDS
        float rs = 0.f;
        #pragma unroll
        for (int n = 0; n < 4; n++) {
            bf4_t pv4;
            #pragma unroll
            for (int r = 0; r < 4; r++) {
                float p = (nib[n] & (1u << r)) ? EXP2F(s[n][r]) : 0.f;
                __bf16 pb = (__bf16)p;
                rs += (float)pb;
                pv4[r] = pb;
            }
            *reinterpret_cast<bf4_t*>(&pw[l16 * 72 + n * 16 + quad * 4]) = pv4;
        }
        rs += __shfl_xor(rs, 16);
        rs += __shfl_xor(rs, 32);
        l_i += rs;

        // O^T += V^T @ P^T over 64 keys (2 chunks)
        #pragma unroll
        for (int c = 0; c < 2; c++) {
            bf8_t pf = *reinterpret_cast<const bf8_t*>(
                &pw[l16 * 72 + c * 32 + quad * 8]);
            #pragma unroll
            for (int ds = 0; ds < 4; ds++) {
                int vrow = ds * 16 + l16;
                bf8_t vf = *reinterpret_cast<const bf8_t*>(
                    &Vs[par][vrow * 64 + (((c * 4 + quad) ^ (vrow & 7)) * 8)]);
                o[ds] = __builtin_amdgcn_mfma_f32_16x16x32_bf16(vf, pf, o[ds], 0, 0, 0);
            }
        }
        // no trailing barrier: next iter writes the other buffer.
    }

    float inv = 1.f / fmaxf(l_i, 1e-30f);
    size_t zrow = ((size_t)b * Tt + qrow + l16) * 1024 + h * 64;
    #pragma unroll
    for (int ds = 0; ds < 4; ds++) {
        bf4_t ov;
        #pragma unroll
        for (int r = 0; r < 4; r++) ov[r] = (__bf16)(o[ds][r] * inv);
        *reinterpret_cast<bf4_t*>(Zb + zrow + ds * 16 + quad * 4) = ov;
    }
}

// ---------------------------------------------------------------- launch
extern "C" void kernel_launch(void* const* d_in, const int* in_sizes, int n_in,
                              void* d_out, int out_size, void* d_ws, size_t ws_size,
                              hipStream_t stream)
{
    (void)in_sizes; (void)n_in; (void)out_size; (void)ws_size;

    const float* embed = (const float*)d_in[0];
    const int*   mask  = (const int*)d_in[1];
    const float* Wq = (const float*)d_in[2];
    const float* bq = (const float*)d_in[3];
    const float* Wk = (const float*)d_in[4];
    const float* bk = (const float*)d_in[5];
    const float* Wv = (const float*)d_in[6];
    const float* bv = (const float*)d_in[7];
    const float* Wz = (const float*)d_in[8];
    const float* bz = (const float*)d_in[9];
    float* out = (float*)d_out;

    char* ws = (char*)d_ws;
    const size_t MB = (size_t)1024 * 1024;
    __bf16*   WqT = (__bf16*)(ws + 0 * MB);
    __bf16*   WkT = (__bf16*)(ws + 2 * MB);
    __bf16*   WvT = (__bf16*)(ws + 4 * MB);
    __bf16*   WzT = (__bf16*)(ws + 6 * MB);
    __bf16*   Eb  = (__bf16*)(ws + 8 * MB);
    __bf16*   Qb  = (__bf16*)(ws + 16 * MB);
    __bf16*   Kb  = (__bf16*)(ws + 24 * MB);
    __bf16*   Vb  = (__bf16*)(ws + 32 * MB);
    __bf16*   Zb  = (__bf16*)(ws + 40 * MB);
    unsigned* Mb  = (unsigned*)(ws + 48 * MB);   // bitmask, 1MB -> total 49MB

    prep_kernel<<<dim3(6144), 256, 0, stream>>>(embed, mask, Wq, Wk, Wv, Wz,
                                                WqT, WkT, WvT, WzT, Eb, Mb);
    gemm_qkv_kernel<<<dim3(8, 32, 3), 256, 0, stream>>>(Eb, WqT, WkT, WvT,
                                                        bq, bk, bv, Qb, Kb, Vb);
    flash_kernel<<<dim3(16, Hh, Bb), 512, 0, stream>>>(Qb, Kb, Vb, Mb, Zb);
    gemm_out_kernel<<<dim3(8, 64, 1), 256, 0, stream>>>(Zb, WzT, bz, out);
}